// Round 1
// baseline (105.360 us; speedup 1.0000x reference)
//
#include <hip/hip_runtime.h>

// 2D Haar DWT: x[B,C,256,256] f32 -> (LL,LH,HL,HH) each [B,C,128,128] f32,
// concatenated flat in d_out. Memory-bound; float4 loads / float2 stores.

constexpr int H  = 256;
constexpr int W  = 256;
constexpr int Ho = H / 2;   // 128
constexpr int Wo = W / 2;   // 128

__global__ __launch_bounds__(256)
void haar_dwt2_kernel(const float* __restrict__ x,
                      float* __restrict__ out,
                      int n_threads,          // BC * Ho * Wo / 2
                      long long band2)        // per-band stride in float2 units
{
    int t = blockIdx.x * blockDim.x + threadIdx.x;
    if (t >= n_threads) return;

    // Each thread: one float4 from each of two adjacent input rows
    // -> 2 output pixels (a float2) in each of the 4 subbands.
    int ox4 = t & (Wo / 2 - 1);         // 0..63 : which float4 group along width
    int rem = t >> 6;
    int oy  = rem & (Ho - 1);           // 0..127
    int bc  = rem >> 7;                 // batch*channel index

    const float* base = x + (size_t)bc * H * W + (size_t)(2 * oy) * W;
    float4 r0 = reinterpret_cast<const float4*>(base)[ox4];
    float4 r1 = reinterpret_cast<const float4*>(base + W)[ox4];

    float2 LL, LH, HL, HH;
    {   // pixel 0: a=r0.x b=r0.y c=r1.x d=r1.y
        float apb = r0.x + r0.y, amb = r0.x - r0.y;
        float cpd = r1.x + r1.y, cmd = r1.x - r1.y;
        LL.x = (apb + cpd) * 0.5f;
        LH.x = (apb - cpd) * 0.5f;
        HL.x = (amb + cmd) * 0.5f;
        HH.x = (amb - cmd) * 0.5f;
    }
    {   // pixel 1: a=r0.z b=r0.w c=r1.z d=r1.w
        float apb = r0.z + r0.w, amb = r0.z - r0.w;
        float cpd = r1.z + r1.w, cmd = r1.z - r1.w;
        LL.y = (apb + cpd) * 0.5f;
        LH.y = (apb - cpd) * 0.5f;
        HL.y = (amb + cmd) * 0.5f;
        HH.y = (amb - cmd) * 0.5f;
    }

    // Output position in float2 units within one band.
    long long o2 = ((long long)bc * Ho + oy) * (Wo / 2) + ox4;
    float2* outp = reinterpret_cast<float2*>(out);
    outp[o2]             = LL;
    outp[band2 + o2]     = LH;
    outp[2 * band2 + o2] = HL;
    outp[3 * band2 + o2] = HH;
}

extern "C" void kernel_launch(void* const* d_in, const int* in_sizes, int n_in,
                              void* d_out, int out_size, void* d_ws, size_t ws_size,
                              hipStream_t stream) {
    const float* x = (const float*)d_in[0];
    float* out = (float*)d_out;

    const long long total_in = in_sizes[0];          // BC * H * W
    const long long BC = total_in / ((long long)H * W);
    const long long band = BC * Ho * Wo;             // elements per subband
    const long long band2 = band / 2;                // in float2 units
    const int n_threads = (int)(band / 2);           // 2 output pixels per thread

    const int block = 256;
    const int grid = (n_threads + block - 1) / block;
    haar_dwt2_kernel<<<grid, block, 0, stream>>>(x, out, n_threads, band2);
}

// Round 3
// 83.274 us; speedup vs baseline: 1.2652x; 1.2652x over previous
//
#include <hip/hip_runtime.h>

// 2D Haar DWT: x[B,C,256,256] f32 -> (LL,LH,HL,HH) each [B,C,128,128] f32,
// concatenated flat in d_out. Memory-bound.
// R3: non-temporal input loads via native ext_vector type (HIP float4 is a
// struct and rejected by __builtin_nontemporal_load).

constexpr int H  = 256;
constexpr int W  = 256;
constexpr int Ho = H / 2;   // 128
constexpr int Wo = W / 2;   // 128

typedef float f32x4 __attribute__((ext_vector_type(4)));
typedef float f32x2 __attribute__((ext_vector_type(2)));

__global__ __launch_bounds__(256)
void haar_dwt2_kernel(const float* __restrict__ x,
                      float* __restrict__ out,
                      int n_threads,          // BC * Ho * Wo / 2
                      long long band2)        // per-band stride in float2 units
{
    int t = blockIdx.x * blockDim.x + threadIdx.x;
    if (t >= n_threads) return;

    // Each thread: one float4 from each of two adjacent input rows
    // -> 2 output pixels (a float2) in each of the 4 subbands.
    int ox4 = t & (Wo / 2 - 1);         // 0..63 : which float4 group along width
    int rem = t >> 6;
    int oy  = rem & (Ho - 1);           // 0..127
    int bc  = rem >> 7;                 // batch*channel index

    const float* base = x + (size_t)bc * H * W + (size_t)(2 * oy) * W;
    const f32x4* p0 = reinterpret_cast<const f32x4*>(base) + ox4;
    const f32x4* p1 = reinterpret_cast<const f32x4*>(base + W) + ox4;
    f32x4 r0 = __builtin_nontemporal_load(p0);
    f32x4 r1 = __builtin_nontemporal_load(p1);

    f32x2 LL, LH, HL, HH;
    {   // pixel 0: a=r0.x b=r0.y c=r1.x d=r1.y
        float apb = r0.x + r0.y, amb = r0.x - r0.y;
        float cpd = r1.x + r1.y, cmd = r1.x - r1.y;
        LL.x = (apb + cpd) * 0.5f;
        LH.x = (apb - cpd) * 0.5f;
        HL.x = (amb + cmd) * 0.5f;
        HH.x = (amb - cmd) * 0.5f;
    }
    {   // pixel 1: a=r0.z b=r0.w c=r1.z d=r1.w
        float apb = r0.z + r0.w, amb = r0.z - r0.w;
        float cpd = r1.z + r1.w, cmd = r1.z - r1.w;
        LL.y = (apb + cpd) * 0.5f;
        LH.y = (apb - cpd) * 0.5f;
        HL.y = (amb + cmd) * 0.5f;
        HH.y = (amb - cmd) * 0.5f;
    }

    // Output position in float2 units within one band.
    long long o2 = ((long long)bc * Ho + oy) * (Wo / 2) + ox4;
    f32x2* outp = reinterpret_cast<f32x2*>(out);
    outp[o2]             = LL;
    outp[band2 + o2]     = LH;
    outp[2 * band2 + o2] = HL;
    outp[3 * band2 + o2] = HH;
}

extern "C" void kernel_launch(void* const* d_in, const int* in_sizes, int n_in,
                              void* d_out, int out_size, void* d_ws, size_t ws_size,
                              hipStream_t stream) {
    const float* x = (const float*)d_in[0];
    float* out = (float*)d_out;

    const long long total_in = in_sizes[0];          // BC * H * W
    const long long BC = total_in / ((long long)H * W);
    const long long band = BC * Ho * Wo;             // elements per subband
    const long long band2 = band / 2;                // in float2 units
    const int n_threads = (int)(band / 2);           // 2 output pixels per thread

    const int block = 256;
    const int grid = (n_threads + block - 1) / block;
    haar_dwt2_kernel<<<grid, block, 0, stream>>>(x, out, n_threads, band2);
}